// Round 1
// baseline (2565.910 us; speedup 1.0000x reference)
//
#include <hip/hip_runtime.h>
#include <cstdint>

#define HD 64
#define NNODES 200000
#define TB 32
#define KC 32

// ---- order-preserving float <-> uint for atomicMax on possibly-negative floats ----
__device__ __forceinline__ unsigned enc_f32(float f) {
    unsigned u = __float_as_uint(f);
    return (u & 0x80000000u) ? ~u : (u | 0x80000000u);
}
__device__ __forceinline__ float dec_f32(unsigned v) {
    return (v & 0x80000000u) ? __uint_as_float(v & 0x7fffffffu)
                             : __uint_as_float(~v);
}

// ---- one dense layer over a 32-row LDS tile ----
// W: [DOUT][DIN] row-major. Xsrc: [TB][DIN+4] LDS tile. Bs: [KC][DOUT+4] staging.
// Each thread: rows {ty, ty+16}, cols {(c*16+tx)*4 + q}.
template<int DIN, int DOUT>
__device__ __forceinline__ void dense_tile(const float* __restrict__ W,
                                           const float* __restrict__ Xsrc,
                                           float* __restrict__ Bs,
                                           int tid, float acc[2][DOUT / 16])
{
    constexpr int PI = DIN + 4;
    constexpr int PB = DOUT + 4;
    const int tx = tid & 15;
    const int ty = tid >> 4;
    for (int k0 = 0; k0 < DIN; k0 += KC) {
        __syncthreads();
        // stage Bs[kk][j] = W[j][k0+kk]; consecutive lanes -> consecutive kk -> coalesced
        for (int lin = tid; lin < KC * DOUT; lin += 256) {
            int j  = lin >> 5;     // KC == 32
            int kk = lin & 31;
            Bs[kk * PB + j] = W[j * DIN + k0 + kk];
        }
        __syncthreads();
        #pragma unroll
        for (int kk = 0; kk < KC; kk++) {
            float xa = Xsrc[ty * PI + k0 + kk];
            float xb = Xsrc[(ty + 16) * PI + k0 + kk];
            #pragma unroll
            for (int c = 0; c < DOUT / 64; c++) {
                const float4 wv = *(const float4*)&Bs[kk * PB + (c * 16 + tx) * 4];
                acc[0][c*4+0] += xa * wv.x;  acc[1][c*4+0] += xb * wv.x;
                acc[0][c*4+1] += xa * wv.y;  acc[1][c*4+1] += xb * wv.y;
                acc[0][c*4+2] += xa * wv.z;  acc[1][c*4+2] += xb * wv.z;
                acc[0][c*4+3] += xa * wv.w;  acc[1][c*4+3] += xb * wv.w;
            }
        }
    }
}

// ---- relation kernel: gather -> MLP(d->d, relu, d->d) -> scatter exp(8*o), track max ----
template<int A>
__global__ __launch_bounds__(256) void rel_kernel(
    const float* __restrict__ ns, const int* __restrict__ idx,
    const float* __restrict__ w1, const float* __restrict__ b1,
    const float* __restrict__ w2, const float* __restrict__ b2,
    float* __restrict__ S, unsigned* __restrict__ Mword)
{
    constexpr int D  = A * HD;
    constexpr int P  = D + 4;
    constexpr int NJ = D / 16;
    __shared__ __align__(16) float Xs[TB * P];
    __shared__ __align__(16) float Hs[TB * P];
    __shared__ __align__(16) float Bs[KC * P];
    __shared__ float wred[4];

    const int tid = threadIdx.x;
    const int tx = tid & 15, ty = tid >> 4;
    const int t0 = blockIdx.x * TB;

    // gather: Xs[t][k] = ns[idx[(t0+t)*A + k/64]*64 + k%64], float4 chunks
    constexpr int K4 = D / 4;
    for (int lin = tid; lin < TB * K4; lin += 256) {
        int t  = lin / K4;
        int k  = (lin - t * K4) * 4;
        int node = idx[(t0 + t) * A + (k >> 6)];
        float4 v = *(const float4*)(ns + (size_t)node * HD + (k & 63));
        *(float4*)&Xs[t * P + k] = v;
    }

    float acc[2][NJ];
    // layer 1
    #pragma unroll
    for (int c = 0; c < NJ / 4; c++) {
        float4 bv = *(const float4*)(b1 + (c * 16 + tx) * 4);
        acc[0][c*4+0]=bv.x; acc[0][c*4+1]=bv.y; acc[0][c*4+2]=bv.z; acc[0][c*4+3]=bv.w;
        acc[1][c*4+0]=bv.x; acc[1][c*4+1]=bv.y; acc[1][c*4+2]=bv.z; acc[1][c*4+3]=bv.w;
    }
    dense_tile<D, D>(w1, Xs, Bs, tid, acc);
    // relu -> Hs
    #pragma unroll
    for (int c = 0; c < NJ / 4; c++) {
        float4 h0, h1;
        h0.x=fmaxf(acc[0][c*4+0],0.f); h0.y=fmaxf(acc[0][c*4+1],0.f);
        h0.z=fmaxf(acc[0][c*4+2],0.f); h0.w=fmaxf(acc[0][c*4+3],0.f);
        h1.x=fmaxf(acc[1][c*4+0],0.f); h1.y=fmaxf(acc[1][c*4+1],0.f);
        h1.z=fmaxf(acc[1][c*4+2],0.f); h1.w=fmaxf(acc[1][c*4+3],0.f);
        *(float4*)&Hs[ty * P + (c * 16 + tx) * 4] = h0;
        *(float4*)&Hs[(ty + 16) * P + (c * 16 + tx) * 4] = h1;
    }
    // layer 2
    #pragma unroll
    for (int c = 0; c < NJ / 4; c++) {
        float4 bv = *(const float4*)(b2 + (c * 16 + tx) * 4);
        acc[0][c*4+0]=bv.x; acc[0][c*4+1]=bv.y; acc[0][c*4+2]=bv.z; acc[0][c*4+3]=bv.w;
        acc[1][c*4+0]=bv.x; acc[1][c*4+1]=bv.y; acc[1][c*4+2]=bv.z; acc[1][c*4+3]=bv.w;
    }
    dense_tile<D, D>(w2, Hs, Bs, tid, acc);

    // epilogue: scatter exp(8*o) into S, track block max of o
    float m = -3.0e38f;
    #pragma unroll
    for (int r = 0; r < 2; r++) {
        int row = (r == 0) ? ty : ty + 16;
        #pragma unroll
        for (int c = 0; c < NJ / 4; c++) {       // chunk c == arity slot (j>>6 == c)
            int node = idx[(t0 + row) * A + c];
            float* dst = S + (size_t)node * HD + tx * 4;
            #pragma unroll
            for (int q = 0; q < 4; q++) {
                float o = acc[r][c*4+q];
                m = fmaxf(m, o);
                atomicAdd(dst + q, __expf(8.f * o));
            }
        }
    }
    #pragma unroll
    for (int off = 32; off; off >>= 1)
        m = fmaxf(m, __shfl_xor(m, off));
    if ((tid & 63) == 0) wred[tid >> 6] = m;
    __syncthreads();
    if (tid == 0) {
        float bm = fmaxf(fmaxf(wred[0], wred[1]), fmaxf(wred[2], wred[3]));
        atomicMax(Mword, enc_f32(bm));
    }
}

// ---- update kernel: max_msg = log(S + 1e-16*exp(8M))/8 ; cat ; MLP(128->128 relu ->64) ----
__global__ __launch_bounds__(256) void update_kernel(
    const float* __restrict__ ns, const float* __restrict__ S,
    const unsigned* __restrict__ Mword,
    const float* __restrict__ uw1, const float* __restrict__ ub1,
    const float* __restrict__ uw2, const float* __restrict__ ub2,
    float* __restrict__ out)
{
    constexpr int D = 2 * HD;   // 128
    constexpr int P = D + 4;
    __shared__ __align__(16) float Xs[TB * P];
    __shared__ __align__(16) float Hs[TB * P];
    __shared__ __align__(16) float Bs[KC * P];

    const int tid = threadIdx.x;
    const int tx = tid & 15, ty = tid >> 4;
    const int r0 = blockIdx.x * TB;

    const float M = dec_f32(*Mword);
    const float corr = 1e-16f * __expf(8.f * M);

    // build cat tile: cols [0,64) = (1/8)log(S+corr), cols [64,128) = node_states
    for (int lin = tid; lin < TB * 32; lin += 256) {
        int t = lin >> 5;
        int k = (lin & 31) * 4;
        float4 v;
        if (k < 64) {
            float4 s = *(const float4*)(S + (size_t)(r0 + t) * HD + k);
            v.x = 0.125f * __logf(s.x + corr);
            v.y = 0.125f * __logf(s.y + corr);
            v.z = 0.125f * __logf(s.z + corr);
            v.w = 0.125f * __logf(s.w + corr);
        } else {
            v = *(const float4*)(ns + (size_t)(r0 + t) * HD + (k - 64));
        }
        *(float4*)&Xs[t * P + k] = v;
    }

    float acc[2][8];
    #pragma unroll
    for (int c = 0; c < 2; c++) {
        float4 bv = *(const float4*)(ub1 + (c * 16 + tx) * 4);
        acc[0][c*4+0]=bv.x; acc[0][c*4+1]=bv.y; acc[0][c*4+2]=bv.z; acc[0][c*4+3]=bv.w;
        acc[1][c*4+0]=bv.x; acc[1][c*4+1]=bv.y; acc[1][c*4+2]=bv.z; acc[1][c*4+3]=bv.w;
    }
    dense_tile<128, 128>(uw1, Xs, Bs, tid, acc);
    #pragma unroll
    for (int c = 0; c < 2; c++) {
        float4 h0, h1;
        h0.x=fmaxf(acc[0][c*4+0],0.f); h0.y=fmaxf(acc[0][c*4+1],0.f);
        h0.z=fmaxf(acc[0][c*4+2],0.f); h0.w=fmaxf(acc[0][c*4+3],0.f);
        h1.x=fmaxf(acc[1][c*4+0],0.f); h1.y=fmaxf(acc[1][c*4+1],0.f);
        h1.z=fmaxf(acc[1][c*4+2],0.f); h1.w=fmaxf(acc[1][c*4+3],0.f);
        *(float4*)&Hs[ty * P + (c * 16 + tx) * 4] = h0;
        *(float4*)&Hs[(ty + 16) * P + (c * 16 + tx) * 4] = h1;
    }
    float acc2[2][4];
    {
        float4 bv = *(const float4*)(ub2 + tx * 4);
        acc2[0][0]=bv.x; acc2[0][1]=bv.y; acc2[0][2]=bv.z; acc2[0][3]=bv.w;
        acc2[1][0]=bv.x; acc2[1][1]=bv.y; acc2[1][2]=bv.z; acc2[1][3]=bv.w;
    }
    dense_tile<128, 64>(uw2, Hs, Bs, tid, acc2);

    float4 o0 = make_float4(acc2[0][0], acc2[0][1], acc2[0][2], acc2[0][3]);
    float4 o1 = make_float4(acc2[1][0], acc2[1][1], acc2[1][2], acc2[1][3]);
    *(float4*)(out + (size_t)(r0 + ty) * HD + tx * 4) = o0;
    *(float4*)(out + (size_t)(r0 + ty + 16) * HD + tx * 4) = o1;
}

extern "C" void kernel_launch(void* const* d_in, const int* in_sizes, int n_in,
                              void* d_out, int out_size, void* d_ws, size_t ws_size,
                              hipStream_t stream)
{
    const float* ns   = (const float*)d_in[0];
    const int*   idx0 = (const int*)d_in[1];
    const int*   idx1 = (const int*)d_in[2];
    const int*   idx2 = (const int*)d_in[3];
    const float* r0w1 = (const float*)d_in[4];  const float* r0b1 = (const float*)d_in[5];
    const float* r0w2 = (const float*)d_in[6];  const float* r0b2 = (const float*)d_in[7];
    const float* r1w1 = (const float*)d_in[8];  const float* r1b1 = (const float*)d_in[9];
    const float* r1w2 = (const float*)d_in[10]; const float* r1b2 = (const float*)d_in[11];
    const float* r2w1 = (const float*)d_in[12]; const float* r2b1 = (const float*)d_in[13];
    const float* r2w2 = (const float*)d_in[14]; const float* r2b2 = (const float*)d_in[15];
    const float* uw1  = (const float*)d_in[16]; const float* ub1  = (const float*)d_in[17];
    const float* uw2  = (const float*)d_in[18]; const float* ub2  = (const float*)d_in[19];

    float*    S  = (float*)d_ws;
    unsigned* Mw = (unsigned*)((char*)d_ws + (size_t)NNODES * HD * sizeof(float));

    // zero the exp-sum accumulator and the max word (ws is poisoned 0xAA each call)
    hipMemsetAsync(d_ws, 0, (size_t)NNODES * HD * sizeof(float) + 64, stream);

    const int T0 = in_sizes[1] / 2;   // 300000
    const int T1 = in_sizes[2] / 2;   // 300000
    const int T2 = in_sizes[3] / 3;   // 200000

    rel_kernel<2><<<T0 / TB, 256, 0, stream>>>(ns, idx0, r0w1, r0b1, r0w2, r0b2, S, Mw);
    rel_kernel<2><<<T1 / TB, 256, 0, stream>>>(ns, idx1, r1w1, r1b1, r1w2, r1b2, S, Mw);
    rel_kernel<3><<<T2 / TB, 256, 0, stream>>>(ns, idx2, r2w1, r2b1, r2w2, r2b2, S, Mw);
    update_kernel<<<NNODES / TB, 256, 0, stream>>>(ns, S, Mw, uw1, ub1, uw2, ub2, (float*)d_out);
}

// Round 2
// 689.093 us; speedup vs baseline: 3.7236x; 3.7236x over previous
//
#include <hip/hip_runtime.h>
#include <cstdint>

#define HD 64
#define NNODES 200000
#define NS_ELEMS (NNODES * HD)          // 12,800,000

typedef short bf8 __attribute__((ext_vector_type(8)));
typedef float f32x4 __attribute__((ext_vector_type(4)));

// ---- order-preserving float <-> uint for atomicMax ----
__device__ __forceinline__ unsigned enc_f32(float f) {
    unsigned u = __float_as_uint(f);
    return (u & 0x80000000u) ? ~u : (u | 0x80000000u);
}
__device__ __forceinline__ float dec_f32(unsigned v) {
    return (v & 0x80000000u) ? __uint_as_float(v & 0x7fffffffu)
                             : __uint_as_float(~v);
}

// RNE float -> bf16 bits
__device__ __forceinline__ ushort f2bf(float f) {
    unsigned u = __float_as_uint(f);
    return (ushort)((u + 0x7fffu + ((u >> 16) & 1u)) >> 16);
}

// ================= prep: ns fp32->bf16; weights fp32 -> bf16 frag-linear =====
// WT layout per matrix: WT[ks][n][kk], ks=k/32, kk=k%32, so a wave's B-frag
// (16 n-values x 32 k) is one contiguous, coalesced 1KB chunk.
struct PrepArgs {
    const float* src[8];
    ushort*      dst[8];
    int din[8], dout[8], nelem[8];
};

__global__ __launch_bounds__(256) void prep_kernel(
    const float* __restrict__ ns, ushort* __restrict__ ns16, PrepArgs pa, int total)
{
    int stride = gridDim.x * 256;
    for (int i = blockIdx.x * 256 + threadIdx.x; i < total; i += stride) {
        if (i < NS_ELEMS) { ns16[i] = f2bf(ns[i]); continue; }
        int e = i - NS_ELEMS;
        #pragma unroll
        for (int m = 0; m < 8; m++) {
            if (e < pa.nelem[m]) {
                int din = pa.din[m], dout = pa.dout[m];
                int n = e / din, k = e - n * din;
                pa.dst[m][(k >> 5) * dout * 32 + n * 32 + (k & 31)] = f2bf(pa.src[m][e]);
                e = 0x7fffffff;
            } else {
                e -= pa.nelem[m];
            }
        }
    }
}

// ================= one MFMA dense layer over a 32-row LDS tile ===============
// Xs: [32][PDIN] bf16 (A-operand layout: row m, col k). WT: frag-linear (above).
// 4 waves; wave w owns output cols [w*NT*16, (w+1)*NT*16).
// acc C/D layout: col = lane&15, row = (lane>>4)*4 + reg.
template<int DIN, int DOUT, int NT, int PDIN>
__device__ __forceinline__ void mfma_layer(
    const ushort* __restrict__ WT, const float* __restrict__ bias,
    const ushort* __restrict__ Xs, int wave, int lane, f32x4 acc[2][NT])
{
    constexpr int KS = DIN / 32;
    const int q = lane >> 4, ln = lane & 15;
    const int n0 = wave * NT * 16;
    bf8 bf[NT][KS];
    #pragma unroll
    for (int nt = 0; nt < NT; nt++) {
        float bv = bias[n0 + nt * 16 + ln];
        acc[0][nt] = f32x4{bv, bv, bv, bv};
        acc[1][nt] = f32x4{bv, bv, bv, bv};
        #pragma unroll
        for (int ks = 0; ks < KS; ks++)
            bf[nt][ks] = *(const bf8*)(WT + (size_t)ks * DOUT * 32
                                          + (n0 + nt * 16 + ln) * 32 + q * 8);
    }
    #pragma unroll
    for (int mt = 0; mt < 2; mt++) {
        bf8 af[KS];
        #pragma unroll
        for (int ks = 0; ks < KS; ks++)
            af[ks] = *(const bf8*)(Xs + (mt * 16 + ln) * PDIN + ks * 32 + q * 8);
        #pragma unroll
        for (int ks = 0; ks < KS; ks++)
            #pragma unroll
            for (int nt = 0; nt < NT; nt++)
                acc[mt][nt] = __builtin_amdgcn_mfma_f32_16x16x32_bf16(
                    af[ks], bf[nt][ks], acc[mt][nt], 0, 0, 0);
    }
}

// ================= relation kernel ==========================================
template<int A>
__global__ __launch_bounds__(256) void rel_mfma(
    const ushort* __restrict__ ns16, const int* __restrict__ idx,
    const ushort* __restrict__ wt1, const float* __restrict__ b1,
    const ushort* __restrict__ wt2, const float* __restrict__ b2,
    float* __restrict__ S, unsigned* __restrict__ Mword)
{
    constexpr int D  = A * HD;
    constexpr int PD = D + 8;           // +16B pad: 2-way LDS aliasing only (free)
    constexpr int NT = D / 64;          // n-tiles per wave (4 waves cover D)
    __shared__ __align__(16) ushort Xs[32 * PD];
    __shared__ __align__(16) ushort Hs[32 * PD];
    __shared__ int Is[32 * A];
    __shared__ float wred[4];

    const int tid = threadIdx.x;
    const int t0  = blockIdx.x * 32;

    if (tid < 32 * A) Is[tid] = idx[t0 * A + tid];
    // gather 32 tuples x A node-rows (128B each) as 16B chunks
    for (int lin = tid; lin < 32 * A * 8; lin += 256) {
        int slot = lin >> 3, part = lin & 7;
        int node = idx[t0 * A + slot];
        int row = slot / A, sub = slot - row * A;
        *(uint4*)(Xs + row * PD + sub * 64 + part * 8) =
            *(const uint4*)(ns16 + (size_t)node * HD + part * 8);
    }
    __syncthreads();

    const int wave = tid >> 6, lane = tid & 63;
    const int q = lane >> 4, ln = lane & 15, n0 = wave * NT * 16;

    f32x4 acc[2][NT];
    mfma_layer<D, D, NT, PD>(wt1, b1, Xs, wave, lane, acc);
    // relu, C-layout -> A-layout via LDS
    #pragma unroll
    for (int mt = 0; mt < 2; mt++)
        #pragma unroll
        for (int nt = 0; nt < NT; nt++)
            #pragma unroll
            for (int r = 0; r < 4; r++)
                Hs[(mt * 16 + q * 4 + r) * PD + n0 + nt * 16 + ln] =
                    f2bf(fmaxf(acc[mt][nt][r], 0.f));
    __syncthreads();
    mfma_layer<D, D, NT, PD>(wt2, b2, Hs, wave, lane, acc);

    // epilogue: scatter exp(8*o), track max o
    float m = -3.0e38f;
    #pragma unroll
    for (int mt = 0; mt < 2; mt++)
        #pragma unroll
        for (int nt = 0; nt < NT; nt++) {
            int colg = n0 + nt * 16 + ln;
            int sub = colg >> 6, feat = colg & 63;
            #pragma unroll
            for (int r = 0; r < 4; r++) {
                int row = mt * 16 + q * 4 + r;
                float o = acc[mt][nt][r];
                m = fmaxf(m, o);
                int node = Is[row * A + sub];
                unsafeAtomicAdd(S + (size_t)node * HD + feat, __expf(8.f * o));
            }
        }
    #pragma unroll
    for (int off = 32; off; off >>= 1) m = fmaxf(m, __shfl_xor(m, off));
    if (lane == 0) wred[wave] = m;
    __syncthreads();
    if (tid == 0)
        atomicMax(Mword, enc_f32(fmaxf(fmaxf(wred[0], wred[1]),
                                       fmaxf(wred[2], wred[3]))));
}

// ================= update kernel ============================================
__global__ __launch_bounds__(256) void update_mfma(
    const float* __restrict__ ns, const float* __restrict__ S,
    const unsigned* __restrict__ Mword,
    const ushort* __restrict__ wt1, const float* __restrict__ b1,
    const ushort* __restrict__ wt2, const float* __restrict__ b2,
    float* __restrict__ out)
{
    constexpr int D = 128, PD = D + 8;
    __shared__ __align__(16) ushort Xs[32 * PD];
    __shared__ __align__(16) ushort Hs[32 * PD];

    const int tid = threadIdx.x;
    const int r0  = blockIdx.x * 32;
    const float corr = 1e-16f * __expf(8.f * dec_f32(*Mword));

    // build cat tile: cols [0,64) = (1/8)log(S+corr); [64,128) = node_states
    for (int lin = tid; lin < 32 * 16; lin += 256) {
        int row = lin >> 4, c8 = (lin & 15) * 8;
        ushort tmp[8];
        if (c8 < 64) {
            #pragma unroll
            for (int j = 0; j < 8; j++) {
                float s = S[(size_t)(r0 + row) * HD + c8 + j];
                tmp[j] = f2bf(0.125f * __logf(s + corr));
            }
        } else {
            #pragma unroll
            for (int j = 0; j < 8; j++)
                tmp[j] = f2bf(ns[(size_t)(r0 + row) * HD + (c8 - 64) + j]);
        }
        *(uint4*)(Xs + row * PD + c8) = *(uint4*)tmp;
    }
    __syncthreads();

    const int wave = tid >> 6, lane = tid & 63;
    const int q = lane >> 4, ln = lane & 15;

    f32x4 acc[2][2];
    mfma_layer<128, 128, 2, PD>(wt1, b1, Xs, wave, lane, acc);
    #pragma unroll
    for (int mt = 0; mt < 2; mt++)
        #pragma unroll
        for (int nt = 0; nt < 2; nt++)
            #pragma unroll
            for (int r = 0; r < 4; r++)
                Hs[(mt * 16 + q * 4 + r) * PD + wave * 32 + nt * 16 + ln] =
                    f2bf(fmaxf(acc[mt][nt][r], 0.f));
    __syncthreads();

    f32x4 acc2[2][1];
    mfma_layer<128, 64, 1, PD>(wt2, b2, Hs, wave, lane, acc2);
    #pragma unroll
    for (int mt = 0; mt < 2; mt++)
        #pragma unroll
        for (int r = 0; r < 4; r++)
            out[(size_t)(r0 + mt * 16 + q * 4 + r) * HD + wave * 16 + ln] =
                acc2[mt][0][r];
}

// ================= host =====================================================
extern "C" void kernel_launch(void* const* d_in, const int* in_sizes, int n_in,
                              void* d_out, int out_size, void* d_ws, size_t ws_size,
                              hipStream_t stream)
{
    const float* ns   = (const float*)d_in[0];
    const int*   idx0 = (const int*)d_in[1];
    const int*   idx1 = (const int*)d_in[2];
    const int*   idx2 = (const int*)d_in[3];
    const float* W[8] = { (const float*)d_in[4],  (const float*)d_in[6],
                          (const float*)d_in[8],  (const float*)d_in[10],
                          (const float*)d_in[12], (const float*)d_in[14],
                          (const float*)d_in[16], (const float*)d_in[18] };
    const float* B[8] = { (const float*)d_in[5],  (const float*)d_in[7],
                          (const float*)d_in[9],  (const float*)d_in[11],
                          (const float*)d_in[13], (const float*)d_in[15],
                          (const float*)d_in[17], (const float*)d_in[19] };
    static const int DIN[8]  = {128,128,128,128,192,192,128,128};
    static const int DOUT[8] = {128,128,128,128,192,192,128, 64};

    // ws layout
    float*    S    = (float*)d_ws;
    size_t    offM = (size_t)NNODES * HD * sizeof(float);      // 51,200,000
    unsigned* Mw   = (unsigned*)((char*)d_ws + offM);
    ushort*   ns16 = (ushort*)((char*)d_ws + offM + 64);
    ushort*   WTb  = ns16 + (size_t)NS_ELEMS;

    PrepArgs pa;
    int total = NS_ELEMS;
    ushort* wt[8];
    {
        ushort* p = WTb;
        for (int m = 0; m < 8; m++) {
            pa.src[m] = W[m];
            pa.dst[m] = p;  wt[m] = p;
            pa.din[m] = DIN[m]; pa.dout[m] = DOUT[m];
            pa.nelem[m] = DIN[m] * DOUT[m];
            p += pa.nelem[m];
            total += pa.nelem[m];
        }
    }

    // zero S + Mword (ws is poisoned each call)
    hipMemsetAsync(d_ws, 0, offM + 64, stream);
    prep_kernel<<<4096, 256, 0, stream>>>(ns, ns16, pa, total);

    const int T0 = in_sizes[1] / 2;   // 300000
    const int T1 = in_sizes[2] / 2;   // 300000
    const int T2 = in_sizes[3] / 3;   // 200000

    rel_mfma<2><<<T0 / 32, 256, 0, stream>>>(ns16, idx0, wt[0], B[0], wt[1], B[1], S, Mw);
    rel_mfma<2><<<T1 / 32, 256, 0, stream>>>(ns16, idx1, wt[2], B[2], wt[3], B[3], S, Mw);
    rel_mfma<3><<<T2 / 32, 256, 0, stream>>>(ns16, idx2, wt[4], B[4], wt[5], B[5], S, Mw);
    update_mfma<<<NNODES / 32, 256, 0, stream>>>(ns, S, Mw, wt[6], B[6], wt[7], B[7],
                                                 (float*)d_out);
}

// Round 3
// 678.464 us; speedup vs baseline: 3.7819x; 1.0157x over previous
//
#include <hip/hip_runtime.h>
#include <hip/hip_bf16.h>
#include <cstdint>

#define HD 64
#define NNODES 200000
#define NS_ELEMS (NNODES * HD)          // 12,800,000

typedef short bf8 __attribute__((ext_vector_type(8)));
typedef short s2v __attribute__((ext_vector_type(2)));
typedef float f32x4 __attribute__((ext_vector_type(4)));

// ---- order-preserving float <-> uint for atomicMax ----
__device__ __forceinline__ unsigned enc_f32(float f) {
    unsigned u = __float_as_uint(f);
    return (u & 0x80000000u) ? ~u : (u | 0x80000000u);
}
__device__ __forceinline__ float dec_f32(unsigned v) {
    return (v & 0x80000000u) ? __uint_as_float(v & 0x7fffffffu)
                             : __uint_as_float(~v);
}

// RNE float -> bf16 bits, and back
__device__ __forceinline__ ushort f2bf(float f) {
    unsigned u = __float_as_uint(f);
    return (ushort)((u + 0x7fffu + ((u >> 16) & 1u)) >> 16);
}
__device__ __forceinline__ float bf2f(ushort b) {
    return __uint_as_float(((unsigned)b) << 16);
}

// ---- packed 2x bf16 atomic add (one 4B atomic op for two feats) ----
__device__ __forceinline__ void atom_pk_add_bf16(ushort* p, ushort lo, ushort hi) {
    s2v v; v[0] = (short)lo; v[1] = (short)hi;
#if __has_builtin(__builtin_amdgcn_flat_atomic_fadd_v2bf16)
    (void)__builtin_amdgcn_flat_atomic_fadd_v2bf16((s2v*)p, v);
#elif __has_builtin(__builtin_amdgcn_global_atomic_fadd_v2bf16)
    (void)__builtin_amdgcn_global_atomic_fadd_v2bf16(
        (__attribute__((address_space(1))) s2v*)p, v);
#else
    // CAS fallback (correct, slow) — only if neither builtin exists
    unsigned* a = (unsigned*)p;
    unsigned old = *a, assumed;
    do {
        assumed = old;
        float f0 = bf2f((ushort)(assumed & 0xffffu)) + bf2f(lo);
        float f1 = bf2f((ushort)(assumed >> 16))     + bf2f(hi);
        unsigned nv = (unsigned)f2bf(f0) | ((unsigned)f2bf(f1) << 16);
        old = atomicCAS(a, assumed, nv);
    } while (old != assumed);
#endif
}

// ================= prep: ns fp32->bf16; weights fp32 -> bf16 frag-linear =====
struct PrepArgs {
    const float* src[8];
    ushort*      dst[8];
    int din[8], dout[8], nelem[8];
};

__global__ __launch_bounds__(256) void prep_kernel(
    const float* __restrict__ ns, ushort* __restrict__ ns16, PrepArgs pa, int total)
{
    int stride = gridDim.x * 256;
    for (int i = blockIdx.x * 256 + threadIdx.x; i < total; i += stride) {
        if (i < NS_ELEMS) { ns16[i] = f2bf(ns[i]); continue; }
        int e = i - NS_ELEMS;
        #pragma unroll
        for (int m = 0; m < 8; m++) {
            if (e < pa.nelem[m]) {
                int din = pa.din[m], dout = pa.dout[m];
                int n = e / din, k = e - n * din;
                pa.dst[m][(k >> 5) * dout * 32 + n * 32 + (k & 31)] = f2bf(pa.src[m][e]);
                e = 0x7fffffff;
            } else {
                e -= pa.nelem[m];
            }
        }
    }
}

// ================= one MFMA dense layer over a 32-row LDS tile ===============
template<int DIN, int DOUT, int NT, int PDIN>
__device__ __forceinline__ void mfma_layer(
    const ushort* __restrict__ WT, const float* __restrict__ bias,
    const ushort* __restrict__ Xs, int wave, int lane, f32x4 acc[2][NT])
{
    constexpr int KS = DIN / 32;
    const int q = lane >> 4, ln = lane & 15;
    const int n0 = wave * NT * 16;
    bf8 bf[NT][KS];
    #pragma unroll
    for (int nt = 0; nt < NT; nt++) {
        float bv = bias[n0 + nt * 16 + ln];
        acc[0][nt] = f32x4{bv, bv, bv, bv};
        acc[1][nt] = f32x4{bv, bv, bv, bv};
        #pragma unroll
        for (int ks = 0; ks < KS; ks++)
            bf[nt][ks] = *(const bf8*)(WT + (size_t)ks * DOUT * 32
                                          + (n0 + nt * 16 + ln) * 32 + q * 8);
    }
    #pragma unroll
    for (int mt = 0; mt < 2; mt++) {
        bf8 af[KS];
        #pragma unroll
        for (int ks = 0; ks < KS; ks++)
            af[ks] = *(const bf8*)(Xs + (mt * 16 + ln) * PDIN + ks * 32 + q * 8);
        #pragma unroll
        for (int ks = 0; ks < KS; ks++)
            #pragma unroll
            for (int nt = 0; nt < NT; nt++)
                acc[mt][nt] = __builtin_amdgcn_mfma_f32_16x16x32_bf16(
                    af[ks], bf[nt][ks], acc[mt][nt], 0, 0, 0);
    }
}

// ================= relation kernel ==========================================
template<int A>
__global__ __launch_bounds__(256) void rel_mfma(
    const ushort* __restrict__ ns16, const int* __restrict__ idx,
    const ushort* __restrict__ wt1, const float* __restrict__ b1,
    const ushort* __restrict__ wt2, const float* __restrict__ b2,
    ushort* __restrict__ S16, unsigned* __restrict__ Mword)
{
    constexpr int D  = A * HD;
    constexpr int PD = D + 8;
    constexpr int NT = D / 64;
    __shared__ __align__(16) ushort Xs[32 * PD];
    __shared__ __align__(16) ushort Hs[32 * PD];
    __shared__ int Is[32 * A];
    __shared__ float wred[4];

    const int tid = threadIdx.x;
    const int t0  = blockIdx.x * 32;

    if (tid < 32 * A) Is[tid] = idx[t0 * A + tid];
    for (int lin = tid; lin < 32 * A * 8; lin += 256) {
        int slot = lin >> 3, part = lin & 7;
        int node = idx[t0 * A + slot];
        int row = slot / A, sub = slot - row * A;
        *(uint4*)(Xs + row * PD + sub * 64 + part * 8) =
            *(const uint4*)(ns16 + (size_t)node * HD + part * 8);
    }
    __syncthreads();

    const int wave = tid >> 6, lane = tid & 63;
    const int q = lane >> 4, ln = lane & 15, n0 = wave * NT * 16;

    f32x4 acc[2][NT];
    mfma_layer<D, D, NT, PD>(wt1, b1, Xs, wave, lane, acc);
    #pragma unroll
    for (int mt = 0; mt < 2; mt++)
        #pragma unroll
        for (int nt = 0; nt < NT; nt++)
            #pragma unroll
            for (int r = 0; r < 4; r++)
                Hs[(mt * 16 + q * 4 + r) * PD + n0 + nt * 16 + ln] =
                    f2bf(fmaxf(acc[mt][nt][r], 0.f));
    __syncthreads();
    mfma_layer<D, D, NT, PD>(wt2, b2, Hs, wave, lane, acc);

    // epilogue: pk-bf16 scatter of exp(8*o); pair feats (2t,2t+1) via lane^1 swap
    float m = -3.0e38f;
    const bool even = (ln & 1) == 0;
    #pragma unroll
    for (int mt = 0; mt < 2; mt++)
        #pragma unroll
        for (int nt = 0; nt < NT; nt++) {
            int colg = n0 + nt * 16 + ln;
            int sub  = colg >> 6;
            int featp = (colg & 63) & ~1;          // even feat of the pair
            float e[4], p[4];
            #pragma unroll
            for (int r = 0; r < 4; r++) {
                float o = acc[mt][nt][r];
                m = fmaxf(m, o);
                e[r] = __expf(8.f * o);
            }
            #pragma unroll
            for (int r = 0; r < 4; r++) p[r] = __shfl_xor(e[r], 1);
            // even lane: rows q*4+{0,1}; odd lane: rows q*4+{2,3}
            #pragma unroll
            for (int j = 0; j < 2; j++) {
                int r   = even ? j : (2 + j);
                int row = mt * 16 + q * 4 + r;
                int node = Is[row * A + sub];
                ushort lo = even ? f2bf(e[r]) : f2bf(p[r]);
                ushort hi = even ? f2bf(p[r]) : f2bf(e[r]);
                atom_pk_add_bf16(S16 + (size_t)node * HD + featp, lo, hi);
            }
        }
    #pragma unroll
    for (int off = 32; off; off >>= 1) m = fmaxf(m, __shfl_xor(m, off));
    if (lane == 0) wred[wave] = m;
    __syncthreads();
    if (tid == 0)
        atomicMax(Mword, enc_f32(fmaxf(fmaxf(wred[0], wred[1]),
                                       fmaxf(wred[2], wred[3]))));
}

// ================= update kernel ============================================
__global__ __launch_bounds__(256) void update_mfma(
    const float* __restrict__ ns, const ushort* __restrict__ S16,
    const unsigned* __restrict__ Mword,
    const ushort* __restrict__ wt1, const float* __restrict__ b1,
    const ushort* __restrict__ wt2, const float* __restrict__ b2,
    float* __restrict__ out)
{
    constexpr int D = 128, PD = D + 8;
    __shared__ __align__(16) ushort Xs[32 * PD];
    __shared__ __align__(16) ushort Hs[32 * PD];

    const int tid = threadIdx.x;
    const int r0  = blockIdx.x * 32;
    const float corr = 1e-16f * __expf(8.f * dec_f32(*Mword));

    for (int lin = tid; lin < 32 * 16; lin += 256) {
        int row = lin >> 4, c8 = (lin & 15) * 8;
        ushort tmp[8];
        if (c8 < 64) {
            ushort raw[8];
            *(uint4*)raw = *(const uint4*)(S16 + (size_t)(r0 + row) * HD + c8);
            #pragma unroll
            for (int j = 0; j < 8; j++)
                tmp[j] = f2bf(0.125f * __logf(bf2f(raw[j]) + corr));
        } else {
            #pragma unroll
            for (int j = 0; j < 8; j++)
                tmp[j] = f2bf(ns[(size_t)(r0 + row) * HD + (c8 - 64) + j]);
        }
        *(uint4*)(Xs + row * PD + c8) = *(uint4*)tmp;
    }
    __syncthreads();

    const int wave = tid >> 6, lane = tid & 63;
    const int q = lane >> 4, ln = lane & 15;

    f32x4 acc[2][2];
    mfma_layer<128, 128, 2, PD>(wt1, b1, Xs, wave, lane, acc);
    #pragma unroll
    for (int mt = 0; mt < 2; mt++)
        #pragma unroll
        for (int nt = 0; nt < 2; nt++)
            #pragma unroll
            for (int r = 0; r < 4; r++)
                Hs[(mt * 16 + q * 4 + r) * PD + wave * 32 + nt * 16 + ln] =
                    f2bf(fmaxf(acc[mt][nt][r], 0.f));
    __syncthreads();

    f32x4 acc2[2][1];
    mfma_layer<128, 64, 1, PD>(wt2, b2, Hs, wave, lane, acc2);
    #pragma unroll
    for (int mt = 0; mt < 2; mt++)
        #pragma unroll
        for (int r = 0; r < 4; r++)
            out[(size_t)(r0 + mt * 16 + q * 4 + r) * HD + wave * 16 + ln] =
                acc2[mt][0][r];
}

// ================= host =====================================================
extern "C" void kernel_launch(void* const* d_in, const int* in_sizes, int n_in,
                              void* d_out, int out_size, void* d_ws, size_t ws_size,
                              hipStream_t stream)
{
    const float* ns   = (const float*)d_in[0];
    const int*   idx0 = (const int*)d_in[1];
    const int*   idx1 = (const int*)d_in[2];
    const int*   idx2 = (const int*)d_in[3];
    const float* W[8] = { (const float*)d_in[4],  (const float*)d_in[6],
                          (const float*)d_in[8],  (const float*)d_in[10],
                          (const float*)d_in[12], (const float*)d_in[14],
                          (const float*)d_in[16], (const float*)d_in[18] };
    const float* B[8] = { (const float*)d_in[5],  (const float*)d_in[7],
                          (const float*)d_in[9],  (const float*)d_in[11],
                          (const float*)d_in[13], (const float*)d_in[15],
                          (const float*)d_in[17], (const float*)d_in[19] };
    static const int DIN[8]  = {128,128,128,128,192,192,128,128};
    static const int DOUT[8] = {128,128,128,128,192,192,128, 64};

    // ws layout: S16 (bf16) | Mword | ns16 | weight frags
    ushort*   S16  = (ushort*)d_ws;
    size_t    offM = (size_t)NNODES * HD * sizeof(ushort);     // 25,600,000
    unsigned* Mw   = (unsigned*)((char*)d_ws + offM);
    ushort*   ns16 = (ushort*)((char*)d_ws + offM + 64);
    ushort*   WTb  = ns16 + (size_t)NS_ELEMS;

    PrepArgs pa;
    int total = NS_ELEMS;
    ushort* wt[8];
    {
        ushort* p = WTb;
        for (int m = 0; m < 8; m++) {
            pa.src[m] = W[m];
            pa.dst[m] = p;  wt[m] = p;
            pa.din[m] = DIN[m]; pa.dout[m] = DOUT[m];
            pa.nelem[m] = DIN[m] * DOUT[m];
            p += pa.nelem[m];
            total += pa.nelem[m];
        }
    }

    hipMemsetAsync(d_ws, 0, offM + 64, stream);
    prep_kernel<<<4096, 256, 0, stream>>>(ns, ns16, pa, total);

    const int T0 = in_sizes[1] / 2;   // 300000
    const int T1 = in_sizes[2] / 2;   // 300000
    const int T2 = in_sizes[3] / 3;   // 200000

    rel_mfma<2><<<T0 / 32, 256, 0, stream>>>(ns16, idx0, wt[0], B[0], wt[1], B[1], S16, Mw);
    rel_mfma<2><<<T1 / 32, 256, 0, stream>>>(ns16, idx1, wt[2], B[2], wt[3], B[3], S16, Mw);
    rel_mfma<3><<<T2 / 32, 256, 0, stream>>>(ns16, idx2, wt[4], B[4], wt[5], B[5], S16, Mw);
    update_mfma<<<NNODES / 32, 256, 0, stream>>>(ns, S16, Mw, wt[6], B[6], wt[7], B[7],
                                                 (float*)d_out);
}